// Round 5
// baseline (210.535 us; speedup 1.0000x reference)
//
#include <hip/hip_runtime.h>
#include <math.h>

// ---------------------------------------------------------------- types
typedef __bf16 bf16_t;
typedef bf16_t bf16x8 __attribute__((ext_vector_type(8)));
typedef float f32x4 __attribute__((ext_vector_type(4)));
typedef unsigned int u32x4 __attribute__((ext_vector_type(4)));

#define S_LEN 2048
#define NHEAD 16
#define DHEAD 64
#define DMODEL 1024
#define BATCH 2

__device__ __forceinline__ float bf2f(unsigned short u) {
    unsigned int x = ((unsigned int)u) << 16;
    return __builtin_bit_cast(float, x);
}
__device__ __forceinline__ unsigned short f2bf(float f) {
    unsigned int x = __builtin_bit_cast(unsigned int, f);
    x += 0x7fffu + ((x >> 16) & 1u);          // RNE
    return (unsigned short)(x >> 16);
}

// async global->LDS, 16B per lane. LDS dest = wave-uniform base + lane*16.
__device__ __forceinline__ void glds16(const void* g, void* l) {
    __builtin_amdgcn_global_load_lds(
        (__attribute__((address_space(1))) void*)g,
        (__attribute__((address_space(3))) void*)l,
        16, 0, 0);
}

#define SCALE2 0.1803368801f   // 1/sqrt(64) * log2(e), folded into Q at qkv epilogue

// ---------------------------------------------------------------- fp32 -> bf16 convert
__global__ __launch_bounds__(256) void cvt_kernel(
    const float* __restrict__ x,  const float* __restrict__ wq,
    const float* __restrict__ wk, const float* __restrict__ wv,
    const float* __restrict__ wo,
    unsigned short* __restrict__ xb,  unsigned short* __restrict__ wqb,
    unsigned short* __restrict__ wkb, unsigned short* __restrict__ wvb,
    unsigned short* __restrict__ wob)
{
    const int y = blockIdx.y;
    const float* s = (y == 0) ? x : (y == 1) ? wq : (y == 2) ? wk : (y == 3) ? wv : wo;
    unsigned short* d = (y == 0) ? xb : (y == 1) ? wqb : (y == 2) ? wkb : (y == 3) ? wvb : wob;
    const int n4 = (y == 0) ? (1 << 20) : (1 << 18);
    const int i = blockIdx.x * 256 + threadIdx.x;
    if (i < n4) {
        float4 v = ((const float4*)s)[i];
        ushort4 o;
        o.x = f2bf(v.x); o.y = f2bf(v.y); o.z = f2bf(v.z); o.w = f2bf(v.w);
        ((ushort4*)d)[i] = o;
    }
}

// ---------------------------------------------------------------- RoPE cos/sin table
__global__ __launch_bounds__(256) void rope_table_kernel(float2* __restrict__ tab)
{
    const int gid = blockIdx.x * 256 + threadIdx.x;   // 65536
    const int s = gid >> 5, d = gid & 31;
    const float freq = exp2f(-0.4152410119f * (float)d);
    const float ang = (float)s * freq;
    tab[gid] = make_float2(cosf(ang), sinf(ang));
}

// ---------------------------------------------------------------- fused QKV GEMM
__global__ __launch_bounds__(256, 2) void qkv_gemm_kernel(
    const unsigned short* __restrict__ xb,
    const unsigned short* __restrict__ wqb, const unsigned short* __restrict__ wkb,
    const unsigned short* __restrict__ wvb,
    const float* __restrict__ bq, const float* __restrict__ bk, const float* __restrict__ bv,
    const float2* __restrict__ tab,
    unsigned short* __restrict__ Qr, unsigned short* __restrict__ Kr,
    unsigned short* __restrict__ VT)
{
    __shared__ __align__(16) unsigned short As[128 * 32];
    __shared__ __align__(16) unsigned short Bs[128 * 32];

    const int which = blockIdx.x >> 3;
    const int bn = (blockIdx.x & 7) * 128;
    const int bm = blockIdx.y * 128;
    const unsigned short* W = (which == 0) ? wqb : (which == 1) ? wkb : wvb;
    const float* bias       = (which == 0) ? bq  : (which == 1) ? bk  : bv;

    const int tid  = threadIdx.x;
    const int lane = tid & 63;
    const int w    = tid >> 6;
    const int quad = lane >> 4;
    const int l16  = lane & 15;
    const int wm   = (w >> 1) * 64;
    const int wn   = (w & 1) * 64;

    f32x4 acc[4][4];
#pragma unroll
    for (int i = 0; i < 4; ++i)
#pragma unroll
        for (int j = 0; j < 4; ++j)
            acc[i][j] = f32x4{0.f, 0.f, 0.f, 0.f};

    const int r0 = tid >> 2, c0 = (tid & 3) * 8;
    const unsigned short* ga0 = xb + (size_t)(bm + r0) * DMODEL + c0;
    const unsigned short* ga1 = ga0 + (size_t)64 * DMODEL;
    const unsigned short* gb0 = W  + (size_t)(bn + r0) * DMODEL + c0;
    const unsigned short* gb1 = gb0 + (size_t)64 * DMODEL;
    unsigned short* la0 = As + tid * 8;
    unsigned short* la1 = As + (tid + 256) * 8;
    unsigned short* lb0 = Bs + tid * 8;
    unsigned short* lb1 = Bs + (tid + 256) * 8;

    for (int k0 = 0; k0 < DMODEL; k0 += 32) {
        glds16(ga0 + k0, la0);
        glds16(ga1 + k0, la1);
        glds16(gb0 + k0, lb0);
        glds16(gb1 + k0, lb1);
        __syncthreads();

        bf16x8 aF[4], bF[4];
#pragma unroll
        for (int t = 0; t < 4; ++t) {
            aF[t] = *(const bf16x8*)(&As[(wm + t * 16 + l16) * 32 + quad * 8]);
            bF[t] = *(const bf16x8*)(&Bs[(wn + t * 16 + l16) * 32 + quad * 8]);
        }
#pragma unroll
        for (int mt = 0; mt < 4; ++mt)
#pragma unroll
            for (int nt = 0; nt < 4; ++nt)
                acc[mt][nt] = __builtin_amdgcn_mfma_f32_16x16x32_bf16(
                    aF[mt], bF[nt], acc[mt][nt], 0, 0, 0);
        __syncthreads();
    }

    // ---- epilogue
    if (which < 2) {
        unsigned short* Y = (which == 0) ? Qr : Kr;
        const float qscale = (which == 0) ? SCALE2 : 1.0f;
#pragma unroll
        for (int mt = 0; mt < 4; ++mt) {
            const int row0 = bm + wm + mt * 16 + quad * 4;
#pragma unroll
            for (int nt = 0; nt < 2; ++nt) {
                const int d   = nt * 16 + l16;       // 0..31 within head
                const int col = bn + wn + nt * 16 + l16;
                const float b1 = bias[col];
                const float b2 = bias[col + 32];
#pragma unroll
                for (int r = 0; r < 4; ++r) {
                    const int row = row0 + r;
                    const int s = row & (S_LEN - 1);
                    const float2 cs = tab[s * 32 + d];
                    const float x1 = acc[mt][nt][r] + b1;
                    const float x2 = acc[mt][nt + 2][r] + b2;
                    Y[(size_t)row * DMODEL + col]      = f2bf((x1 * cs.x - x2 * cs.y) * qscale);
                    Y[(size_t)row * DMODEL + col + 32] = f2bf((x2 * cs.x + x1 * cs.y) * qscale);
                }
            }
        }
    } else {
#pragma unroll
        for (int mt = 0; mt < 4; ++mt) {
            const int row0 = bm + wm + mt * 16 + quad * 4;
            const int bb = row0 >> 11, s0 = row0 & (S_LEN - 1);
            const int h = (bn + wn) >> 6;
#pragma unroll
            for (int nt = 0; nt < 4; ++nt) {
                const int d = nt * 16 + l16;
                const float bv2 = bias[bn + wn + nt * 16 + l16];
                unsigned short pk[4];
#pragma unroll
                for (int r = 0; r < 4; ++r)
                    pk[r] = f2bf(acc[mt][nt][r] + bv2);
                *(uint2*)(&VT[((size_t)(bb * NHEAD + h) * DHEAD + d) * S_LEN + s0]) =
                    *(const uint2*)pk;
            }
        }
    }
}

// ---------------------------------------------------------------- attention
// Round-15: halve LDS redundancy. Model from r4 counters: each wave reads
// the ENTIRE staged K,V tile (32 KB) per stage; 8 waves/block = 256 KB LDS
// reads/stage ~ 3.1k cyc -- the dominant term (~40% of measured cycles).
// Fix: 256-thread blocks (4 waves), each wave owns 32 q-rows as two 16-row
// groups processed serially per stage (g-loop) -> 128 KB/stage, same stage
// count, total LDS traffic halved. Keeps r4's verified in-register P
// (swapped QK^T + cvt_pk + shfl redistribute), dbuf + counted vmcnt, and
// the 512-block complementary-pair grid (2 blocks/CU, LDS 64 KB).
__global__ __launch_bounds__(256, 2) void attn_kernel(
    const unsigned short* __restrict__ Q, const unsigned short* __restrict__ K,
    const unsigned short* __restrict__ VT, unsigned short* __restrict__ O)
{
    const int j  = blockIdx.x;          // 0..511
    const int bh = j & 31;
    const int qs = j >> 5;              // 0..15
    const int b  = bh >> 4, h = bh & 15;
    const int qt = (qs < 8) ? (15 - qs) : (qs - 8);

    const int tid  = threadIdx.x;
    const int w    = tid >> 6;          // 0..3
    const int lane = tid & 63;
    const int quad = lane >> 4;
    const int l16  = lane & 15;

    __shared__ __align__(16) unsigned short Ks[2][128 * 64];   // [kpos][dh]  swizzled
    __shared__ __align__(16) unsigned short Vt[2][64 * 128];   // [dh][kpos] swizzled

    const int q0 = qt * 128;
    const unsigned short* Qb = Q  + (size_t)b * S_LEN * DMODEL + h * DHEAD;
    const unsigned short* Kb = K  + (size_t)b * S_LEN * DMODEL + h * DHEAD;
    const unsigned short* Vh = VT + ((size_t)(b * NHEAD + h)) * DHEAD * S_LEN;

    // Q fragments (B-operand of swapped QK^T), two groups:
    // rows q0 + g*64 + w*16 + l16
    bf16x8 qf[2][2];
#pragma unroll
    for (int g = 0; g < 2; ++g) {
        const int qrow = q0 + g * 64 + w * 16 + l16;
        qf[g][0] = *(const bf16x8*)(Qb + (size_t)qrow * DMODEL + quad * 8);
        qf[g][1] = *(const bf16x8*)(Qb + (size_t)qrow * DMODEL + 32 + quad * 8);
    }

    f32x4 o[2][4];
#pragma unroll
    for (int g = 0; g < 2; ++g)
#pragma unroll
        for (int i = 0; i < 4; ++i) o[g][i] = f32x4{0.f, 0.f, 0.f, 0.f};
    float l_acc[2] = {0.f, 0.f};

    const int nkt = qt + 1;

#define STAGE(bs, kt_) do {                                                        \
        _Pragma("unroll")                                                          \
        for (int i_ = 0; i_ < 4; ++i_) {                                           \
            const int ck = tid + i_ * 256;                                         \
            const int krow = ck >> 3, kc = ck & 7;                                 \
            glds16(Kb + (size_t)((kt_) * 128 + krow) * DMODEL + ((kc ^ (krow & 7)) * 8), \
                   &Ks[bs][ck * 8]);                                               \
            const int vrow = ck >> 4, vc = ck & 15;                                \
            glds16(Vh + (size_t)vrow * S_LEN + (kt_) * 128 + ((vc ^ (vrow & 15)) * 8), \
                   &Vt[bs][ck * 8]);                                               \
        }                                                                          \
    } while (0)

    STAGE(0, 0);

    for (int kt = 0; kt < nkt; ++kt) {
        const int cur = kt & 1;

        if (kt + 1 < nkt) {
            STAGE(cur ^ 1, kt + 1);
            asm volatile("s_waitcnt vmcnt(8)" ::: "memory");   // prev stage's 8 done
        } else {
            asm volatile("s_waitcnt vmcnt(0)" ::: "memory");
        }
        __builtin_amdgcn_s_barrier();   // barrier A: buf[cur] staged for all waves

        const bool diag = (kt == qt);

#pragma unroll
        for (int g = 0; g < 2; ++g) {
            // group g's rows only see kpos <= q0+g*64+w*16+15 on the diagonal;
            // round up to a 32-kpos block so masked entries are exact zeros.
            const int ntmax = diag ? (((g * 4 + w) & ~1) + 2) : 8;
            const int cmax  = ntmax >> 1;

            // ---- scores (swapped): lane holds q=l16, kpos=kt*128+nt*16+quad*4+r
            f32x4 sc[8];
#pragma unroll
            for (int nt = 0; nt < 8; ++nt) {
                if (nt >= ntmax) break;
                const int row = nt * 16 + l16;
                const bf16x8 kf0 = *(const bf16x8*)(&Ks[cur][row * 64 + ((quad ^ (l16 & 7)) * 8)]);
                const bf16x8 kf1 = *(const bf16x8*)(&Ks[cur][row * 64 + (((4 + quad) ^ (l16 & 7)) * 8)]);
                f32x4 a = f32x4{0.f, 0.f, 0.f, 0.f};
                a = __builtin_amdgcn_mfma_f32_16x16x32_bf16(kf0, qf[g][0], a, 0, 0, 0);
                a = __builtin_amdgcn_mfma_f32_16x16x32_bf16(kf1, qf[g][1], a, 0, 0, 0);
                sc[nt] = a;
            }

            if (diag) {   // mask kpos > qpos; kpos-in-tile = nt*16 + quad*4 + r
                const int thr = q0 + g * 64 + w * 16 + l16 - kt * 128 - quad * 4;
#pragma unroll
                for (int nt = 0; nt < 8; ++nt) {
                    if (nt >= ntmax) break;
#pragma unroll
                    for (int r = 0; r < 4; ++r)
                        if (nt * 16 + r > thr) sc[nt][r] = -INFINITY;
                }
            }

            // ---- exp2 + row-sum (lane owns one q-row: scalar accumulator)
#pragma unroll
            for (int nt = 0; nt < 8; ++nt) {
                if (nt >= ntmax) break;
#pragma unroll
                for (int r = 0; r < 4; ++r) {
                    const float e = exp2f(sc[nt][r]);
                    sc[nt][r] = e;
                    l_acc[g] += e;
                }
            }

            // ---- P -> PV A-frags in registers (verified r4 mapping)
            bf16x8 pA[4];
            const bool qlo = (quad < 2);
#pragma unroll
            for (int c = 0; c < 4; ++c) {
                if (c >= cmax) break;
                unsigned int s0, s1, t0, t1;
                asm("v_cvt_pk_bf16_f32 %0, %1, %2" : "=v"(s0) : "v"(sc[2*c][0]),   "v"(sc[2*c][1]));
                asm("v_cvt_pk_bf16_f32 %0, %1, %2" : "=v"(s1) : "v"(sc[2*c][2]),   "v"(sc[2*c][3]));
                asm("v_cvt_pk_bf16_f32 %0, %1, %2" : "=v"(t0) : "v"(sc[2*c+1][0]), "v"(sc[2*c+1][1]));
                asm("v_cvt_pk_bf16_f32 %0, %1, %2" : "=v"(t1) : "v"(sc[2*c+1][2]), "v"(sc[2*c+1][3]));
                const unsigned int m0 = qlo ? s0 : t0, m1 = qlo ? s1 : t1;
                const unsigned int n0 = qlo ? t0 : s0, n1 = qlo ? t1 : s1;
                const unsigned int X0 = __shfl_xor(m0, 16), X1 = __shfl_xor(m1, 16);
                const unsigned int A0 = __shfl_xor(n0, 32), A1 = __shfl_xor(n1, 32);
                const unsigned int B0 = __shfl_xor(n0, 48), B1 = __shfl_xor(n1, 48);
                u32x4 aw;
                aw[0] = qlo ? (quad == 0 ? m0 : B0) : (quad == 2 ? A0 : X0);
                aw[1] = qlo ? (quad == 0 ? m1 : B1) : (quad == 2 ? A1 : X1);
                aw[2] = qlo ? (quad == 0 ? X0 : A0) : (quad == 2 ? B0 : m0);
                aw[3] = qlo ? (quad == 0 ? X1 : A1) : (quad == 2 ? B1 : m1);
                pA[c] = __builtin_bit_cast(bf16x8, aw);
            }

#pragma unroll
            for (int nt = 0; nt < 4; ++nt) {
                const int row = nt * 16 + l16;
#pragma unroll
                for (int c = 0; c < 4; ++c) {
                    if (c >= cmax) break;
                    const bf16x8 vF = *(const bf16x8*)(&Vt[cur][row * 128 + (((c * 4 + quad) ^ l16) * 8)]);
                    o[g][nt] = __builtin_amdgcn_mfma_f32_16x16x32_bf16(pA[c], vF, o[g][nt], 0, 0, 0);
                }
            }
        }

        asm volatile("s_waitcnt lgkmcnt(0)" ::: "memory");
        __builtin_amdgcn_s_barrier();   // barrier B: buf[cur] reads done everywhere
    }
#undef STAGE

    // ---- epilogue: row-sum reduce over quads, normalize, store (per group)
#pragma unroll
    for (int g = 0; g < 2; ++g) {
        float rs = l_acc[g];
        rs += __shfl_xor(rs, 16);
        rs += __shfl_xor(rs, 32);       // full sum for q = l16, uniform over quads
        const float linv_row = 1.0f / rs;
        float linv[4];
#pragma unroll
        for (int r = 0; r < 4; ++r)
            linv[r] = __shfl(linv_row, quad * 4 + r);   // l for q-row = quad*4+r

        const int spos0 = q0 + g * 64 + w * 16 + quad * 4;
#pragma unroll
        for (int nt = 0; nt < 4; ++nt)
#pragma unroll
            for (int r = 0; r < 4; ++r) {
                const float val = o[g][nt][r] * linv[r];
                O[((size_t)b * S_LEN + spos0 + r) * DMODEL + h * DHEAD + nt * 16 + l16] = f2bf(val);
            }
    }
}

// ---------------------------------------------------------------- out-proj GEMM (bf16 x bf16 -> fp32)
__global__ __launch_bounds__(256, 2) void outproj_kernel(
    const unsigned short* __restrict__ A, const unsigned short* __restrict__ W,
    const float* __restrict__ bias, float* __restrict__ C)
{
    __shared__ __align__(16) unsigned short As[64 * 32];
    __shared__ __align__(16) unsigned short Bs[128 * 32];

    const int tid  = threadIdx.x;
    const int lane = tid & 63;
    const int w    = tid >> 6;
    const int quad = lane >> 4;
    const int l16  = lane & 15;
    const int wm   = (w >> 1) * 32;
    const int wn   = (w & 1) * 64;
    const int bm   = blockIdx.y * 64;
    const int bn   = blockIdx.x * 128;

    f32x4 acc[2][4];
#pragma unroll
    for (int i = 0; i < 2; ++i)
#pragma unroll
        for (int j = 0; j < 4; ++j)
            acc[i][j] = f32x4{0.f, 0.f, 0.f, 0.f};

    const int r0 = tid >> 2, c0 = (tid & 3) * 8;
    const unsigned short* ga  = A + (size_t)(bm + r0) * DMODEL + c0;
    const unsigned short* gb0 = W + (size_t)(bn + r0) * DMODEL + c0;
    const unsigned short* gb1 = gb0 + (size_t)64 * DMODEL;
    unsigned short* la  = As + tid * 8;
    unsigned short* lb0 = Bs + tid * 8;
    unsigned short* lb1 = Bs + (tid + 256) * 8;

    for (int k0 = 0; k0 < DMODEL; k0 += 32) {
        glds16(ga + k0, la);
        glds16(gb0 + k0, lb0);
        glds16(gb1 + k0, lb1);
        __syncthreads();

        bf16x8 aF[2], bF[4];
#pragma unroll
        for (int t = 0; t < 2; ++t)
            aF[t] = *(const bf16x8*)(&As[(wm + t * 16 + l16) * 32 + quad * 8]);
#pragma unroll
        for (int t = 0; t < 4; ++t)
            bF[t] = *(const bf16x8*)(&Bs[(wn + t * 16 + l16) * 32 + quad * 8]);
#pragma unroll
        for (int mt = 0; mt < 2; ++mt)
#pragma unroll
            for (int nt = 0; nt < 4; ++nt)
                acc[mt][nt] = __builtin_amdgcn_mfma_f32_16x16x32_bf16(
                    aF[mt], bF[nt], acc[mt][nt], 0, 0, 0);
        __syncthreads();
    }

#pragma unroll
    for (int mt = 0; mt < 2; ++mt) {
        const int row0 = bm + wm + mt * 16 + quad * 4;
#pragma unroll
        for (int nt = 0; nt < 4; ++nt) {
            const int col = bn + wn + nt * 16 + l16;
            const float bv = bias[col];
#pragma unroll
            for (int r = 0; r < 4; ++r)
                C[(size_t)(row0 + r) * DMODEL + col] = acc[mt][nt][r] + bv;
        }
    }
}

// ---------------------------------------------------------------- launch
extern "C" void kernel_launch(void* const* d_in, const int* in_sizes, int n_in,
                              void* d_out, int out_size, void* d_ws, size_t ws_size,
                              hipStream_t stream) {
    const float* x  = (const float*)d_in[0];
    const float* Wq = (const float*)d_in[1];
    const float* bq = (const float*)d_in[2];
    const float* Wk = (const float*)d_in[3];
    const float* bk = (const float*)d_in[4];
    const float* Wv = (const float*)d_in[5];
    const float* bv = (const float*)d_in[6];
    const float* Wo = (const float*)d_in[7];
    const float* bo = (const float*)d_in[8];
    float* out = (float*)d_out;

    char* ws = (char*)d_ws;
    const size_t MB = 1 << 20;
    unsigned short* xb  = (unsigned short*)(ws);            //  8 MB
    unsigned short* wqb = (unsigned short*)(ws + 8  * MB);  //  2 MB each
    unsigned short* wkb = (unsigned short*)(ws + 10 * MB);
    unsigned short* wvb = (unsigned short*)(ws + 12 * MB);
    unsigned short* wob = (unsigned short*)(ws + 14 * MB);
    float2*         tab = (float2*)       (ws + 16 * MB);   // 512 KB
    unsigned short* Qr  = (unsigned short*)(ws + 17 * MB);  //  8 MB
    unsigned short* Kr  = (unsigned short*)(ws + 25 * MB);
    unsigned short* VT  = (unsigned short*)(ws + 33 * MB);
    unsigned short* AO  = (unsigned short*)(ws + 41 * MB);

    const int M = BATCH * S_LEN;   // 4096

    cvt_kernel<<<dim3(4096, 5), 256, 0, stream>>>(
        x, Wq, Wk, Wv, Wo, xb, wqb, wkb, wvb, wob);

    rope_table_kernel<<<256, 256, 0, stream>>>(tab);

    qkv_gemm_kernel<<<dim3(24, M / 128), 256, 0, stream>>>(
        xb, wqb, wkb, wvb, bq, bk, bv, tab, Qr, Kr, VT);

    attn_kernel<<<dim3(512), 256, 0, stream>>>(Qr, Kr, VT, AO);

    outproj_kernel<<<dim3(DMODEL / 128, M / 64), 256, 0, stream>>>(AO, wob, bo, out);
}

// Round 6
// 196.023 us; speedup vs baseline: 1.0740x; 1.0740x over previous
//
#include <hip/hip_runtime.h>
#include <math.h>

// ---------------------------------------------------------------- types
typedef __bf16 bf16_t;
typedef bf16_t bf16x8 __attribute__((ext_vector_type(8)));
typedef float f32x4 __attribute__((ext_vector_type(4)));
typedef unsigned int u32x4 __attribute__((ext_vector_type(4)));

#define S_LEN 2048
#define NHEAD 16
#define DHEAD 64
#define DMODEL 1024
#define BATCH 2

__device__ __forceinline__ float bf2f(unsigned short u) {
    unsigned int x = ((unsigned int)u) << 16;
    return __builtin_bit_cast(float, x);
}
__device__ __forceinline__ unsigned short f2bf(float f) {
    unsigned int x = __builtin_bit_cast(unsigned int, f);
    x += 0x7fffu + ((x >> 16) & 1u);          // RNE
    return (unsigned short)(x >> 16);
}

// async global->LDS, 16B per lane. LDS dest = wave-uniform base + lane*16.
__device__ __forceinline__ void glds16(const void* g, void* l) {
    __builtin_amdgcn_global_load_lds(
        (__attribute__((address_space(1))) void*)g,
        (__attribute__((address_space(3))) void*)l,
        16, 0, 0);
}

#define SCALE2 0.1803368801f   // 1/sqrt(64) * log2(e), folded into Q at qkv epilogue

// ---------------------------------------------------------------- fp32 -> bf16 convert
// Exact-sized 1-D grid: 4096 blocks for x (1M float4), 1024 per weight.
__global__ __launch_bounds__(256) void cvt_kernel(
    const float* __restrict__ x,  const float* __restrict__ wq,
    const float* __restrict__ wk, const float* __restrict__ wv,
    const float* __restrict__ wo,
    unsigned short* __restrict__ xb,  unsigned short* __restrict__ wqb,
    unsigned short* __restrict__ wkb, unsigned short* __restrict__ wvb,
    unsigned short* __restrict__ wob)
{
    const int bid = blockIdx.x;          // 0..8191
    const float* s;
    unsigned short* d;
    int i;
    if (bid < 4096) {
        s = x; d = xb; i = bid * 256 + threadIdx.x;
    } else {
        const int k = (bid - 4096) >> 10;           // 0..3
        s = (k == 0) ? wq : (k == 1) ? wk : (k == 2) ? wv : wo;
        d = (k == 0) ? wqb : (k == 1) ? wkb : (k == 2) ? wvb : wob;
        i = ((bid - 4096) & 1023) * 256 + threadIdx.x;
    }
    float4 v = ((const float4*)s)[i];
    ushort4 o;
    o.x = f2bf(v.x); o.y = f2bf(v.y); o.z = f2bf(v.z); o.w = f2bf(v.w);
    ((ushort4*)d)[i] = o;
}

// ---------------------------------------------------------------- RoPE cos/sin table
__global__ __launch_bounds__(256) void rope_table_kernel(float2* __restrict__ tab)
{
    const int gid = blockIdx.x * 256 + threadIdx.x;   // 65536
    const int s = gid >> 5, d = gid & 31;
    const float freq = exp2f(-0.4152410119f * (float)d);
    const float ang = (float)s * freq;
    tab[gid] = make_float2(cosf(ang), sinf(ang));
}

// ---------------------------------------------------------------- fused QKV GEMM
// BK=64 (was 32): halves barrier count (16 K-steps x 2 barriers), amortizing
// the per-step vmcnt(0)+barrier drain. LDS 32 KB; epilogues unchanged.
__global__ __launch_bounds__(256, 2) void qkv_gemm_kernel(
    const unsigned short* __restrict__ xb,
    const unsigned short* __restrict__ wqb, const unsigned short* __restrict__ wkb,
    const unsigned short* __restrict__ wvb,
    const float* __restrict__ bq, const float* __restrict__ bk, const float* __restrict__ bv,
    const float2* __restrict__ tab,
    unsigned short* __restrict__ Qr, unsigned short* __restrict__ Kr,
    unsigned short* __restrict__ VT)
{
    __shared__ __align__(16) unsigned short As[128 * 64];
    __shared__ __align__(16) unsigned short Bs[128 * 64];

    const int which = blockIdx.x >> 3;
    const int bn = (blockIdx.x & 7) * 128;
    const int bm = blockIdx.y * 128;
    const unsigned short* W = (which == 0) ? wqb : (which == 1) ? wkb : wvb;
    const float* bias       = (which == 0) ? bq  : (which == 1) ? bk  : bv;

    const int tid  = threadIdx.x;
    const int lane = tid & 63;
    const int w    = tid >> 6;
    const int quad = lane >> 4;
    const int l16  = lane & 15;
    const int wm   = (w >> 1) * 64;
    const int wn   = (w & 1) * 64;

    f32x4 acc[4][4];
#pragma unroll
    for (int i = 0; i < 4; ++i)
#pragma unroll
        for (int j = 0; j < 4; ++j)
            acc[i][j] = f32x4{0.f, 0.f, 0.f, 0.f};

    // staging: 128 rows x 64 cols per tile; thread ck = tid + i*256,
    // row = (tid>>3) + i*32, colblk = tid&7. Dest linear As + ck*8.
    const int r8 = tid >> 3, c8 = (tid & 7) * 8;
    const unsigned short* ga = xb + (size_t)(bm + r8) * DMODEL + c8;
    const unsigned short* gb = W  + (size_t)(bn + r8) * DMODEL + c8;
    unsigned short* la = As + tid * 8;
    unsigned short* lb = Bs + tid * 8;

    for (int k0 = 0; k0 < DMODEL; k0 += 64) {
#pragma unroll
        for (int i = 0; i < 4; ++i) {
            glds16(ga + k0 + (size_t)(i * 32) * DMODEL, la + i * 2048);
            glds16(gb + k0 + (size_t)(i * 32) * DMODEL, lb + i * 2048);
        }
        __syncthreads();

        bf16x8 aF[2][4], bF[2][4];
#pragma unroll
        for (int ks = 0; ks < 2; ++ks)
#pragma unroll
            for (int t = 0; t < 4; ++t) {
                aF[ks][t] = *(const bf16x8*)(&As[(wm + t * 16 + l16) * 64 + ks * 32 + quad * 8]);
                bF[ks][t] = *(const bf16x8*)(&Bs[(wn + t * 16 + l16) * 64 + ks * 32 + quad * 8]);
            }
#pragma unroll
        for (int ks = 0; ks < 2; ++ks)
#pragma unroll
            for (int mt = 0; mt < 4; ++mt)
#pragma unroll
                for (int nt = 0; nt < 4; ++nt)
                    acc[mt][nt] = __builtin_amdgcn_mfma_f32_16x16x32_bf16(
                        aF[ks][mt], bF[ks][nt], acc[mt][nt], 0, 0, 0);
        __syncthreads();
    }

    // ---- epilogue
    if (which < 2) {
        unsigned short* Y = (which == 0) ? Qr : Kr;
        const float qscale = (which == 0) ? SCALE2 : 1.0f;
#pragma unroll
        for (int mt = 0; mt < 4; ++mt) {
            const int row0 = bm + wm + mt * 16 + quad * 4;
#pragma unroll
            for (int nt = 0; nt < 2; ++nt) {
                const int d   = nt * 16 + l16;       // 0..31 within head
                const int col = bn + wn + nt * 16 + l16;
                const float b1 = bias[col];
                const float b2 = bias[col + 32];
#pragma unroll
                for (int r = 0; r < 4; ++r) {
                    const int row = row0 + r;
                    const int s = row & (S_LEN - 1);
                    const float2 cs = tab[s * 32 + d];
                    const float x1 = acc[mt][nt][r] + b1;
                    const float x2 = acc[mt][nt + 2][r] + b2;
                    Y[(size_t)row * DMODEL + col]      = f2bf((x1 * cs.x - x2 * cs.y) * qscale);
                    Y[(size_t)row * DMODEL + col + 32] = f2bf((x2 * cs.x + x1 * cs.y) * qscale);
                }
            }
        }
    } else {
#pragma unroll
        for (int mt = 0; mt < 4; ++mt) {
            const int row0 = bm + wm + mt * 16 + quad * 4;
            const int bb = row0 >> 11, s0 = row0 & (S_LEN - 1);
            const int h = (bn + wn) >> 6;
#pragma unroll
            for (int nt = 0; nt < 4; ++nt) {
                const int d = nt * 16 + l16;
                const float bv2 = bias[bn + wn + nt * 16 + l16];
                unsigned short pk[4];
#pragma unroll
                for (int r = 0; r < 4; ++r)
                    pk[r] = f2bf(acc[mt][nt][r] + bv2);
                *(uint2*)(&VT[((size_t)(bb * NHEAD + h) * DHEAD + d) * S_LEN + s0]) =
                    *(const uint2*)pk;
            }
        }
    }
}

// ---------------------------------------------------------------- attention
// Round-16: exact r4 revert (best verified: 54.4 us, conflicts 0, FETCH 12 MB).
// r5's 4-wave g-loop variant regressed (68.6): kernel is latency-bound, not
// LDS-BW-bound -- halving waves/block doubled the per-wave serial chain.
// Only change vs r4: vmcnt(8) -> vmcnt(4) (the correct count: 4 glds/wave
// per stage; 8 was a benign no-op given stage time >> load latency).
__global__ __launch_bounds__(512, 4) void attn_kernel(
    const unsigned short* __restrict__ Q, const unsigned short* __restrict__ K,
    const unsigned short* __restrict__ VT, unsigned short* __restrict__ O)
{
    const int j  = blockIdx.x;          // 0..511
    const int bh = j & 31;
    const int qs = j >> 5;              // 0..15
    const int b  = bh >> 4, h = bh & 15;
    const int qt = (qs < 8) ? (15 - qs) : (qs - 8);

    const int tid  = threadIdx.x;
    const int w    = tid >> 6;          // 0..7
    const int lane = tid & 63;
    const int quad = lane >> 4;
    const int l16  = lane & 15;

    __shared__ __align__(16) unsigned short Ks[2][128 * 64];   // [kpos][dh]  swizzled
    __shared__ __align__(16) unsigned short Vt[2][64 * 128];   // [dh][kpos] swizzled

    const int q0 = qt * 128;
    const unsigned short* Qb = Q  + (size_t)b * S_LEN * DMODEL + h * DHEAD;
    const unsigned short* Kb = K  + (size_t)b * S_LEN * DMODEL + h * DHEAD;
    const unsigned short* Vh = VT + ((size_t)(b * NHEAD + h)) * DHEAD * S_LEN;

    // Q fragment (B-operand of swapped QK^T): rows q0 + w*16 + l16
    const int qrow = q0 + w * 16 + l16;
    const bf16x8 qf0 = *(const bf16x8*)(Qb + (size_t)qrow * DMODEL + quad * 8);
    const bf16x8 qf1 = *(const bf16x8*)(Qb + (size_t)qrow * DMODEL + 32 + quad * 8);

    f32x4 o[4];
#pragma unroll
    for (int i = 0; i < 4; ++i) o[i] = f32x4{0.f, 0.f, 0.f, 0.f};
    float l_acc = 0.f;

    const int nkt = qt + 1;

#define STAGE(bs, kt_) do {                                                        \
        _Pragma("unroll")                                                          \
        for (int i_ = 0; i_ < 2; ++i_) {                                           \
            const int ck = tid + i_ * 512;                                         \
            const int krow = ck >> 3, kc = ck & 7;                                 \
            glds16(Kb + (size_t)((kt_) * 128 + krow) * DMODEL + ((kc ^ (krow & 7)) * 8), \
                   &Ks[bs][ck * 8]);                                               \
            const int vrow = ck >> 4, vc = ck & 15;                                \
            glds16(Vh + (size_t)vrow * S_LEN + (kt_) * 128 + ((vc ^ (vrow & 15)) * 8), \
                   &Vt[bs][ck * 8]);                                               \
        }                                                                          \
    } while (0)

    STAGE(0, 0);

    for (int kt = 0; kt < nkt; ++kt) {
        const int cur = kt & 1;

        if (kt + 1 < nkt) {
            STAGE(cur ^ 1, kt + 1);
            asm volatile("s_waitcnt vmcnt(4)" ::: "memory");   // prev stage's 4 done
        } else {
            asm volatile("s_waitcnt vmcnt(0)" ::: "memory");
        }
        __builtin_amdgcn_s_barrier();   // barrier A: buf[cur] staged for all waves

        const bool diag = (kt == qt);
        const int ntmax = diag ? ((w & ~1) + 2) : 8;
        const int cmax  = ntmax >> 1;

        // ---- scores (swapped): sc[nt] = S^T fragment, lane: q=l16,
        //      kpos = kt*128 + nt*16 + quad*4 + r
        f32x4 sc[8];
#pragma unroll
        for (int nt = 0; nt < 8; ++nt) {
            if (nt >= ntmax) break;
            const int row = nt * 16 + l16;
            const bf16x8 kf0 = *(const bf16x8*)(&Ks[cur][row * 64 + ((quad ^ (l16 & 7)) * 8)]);
            const bf16x8 kf1 = *(const bf16x8*)(&Ks[cur][row * 64 + (((4 + quad) ^ (l16 & 7)) * 8)]);
            f32x4 a = f32x4{0.f, 0.f, 0.f, 0.f};
            a = __builtin_amdgcn_mfma_f32_16x16x32_bf16(kf0, qf0, a, 0, 0, 0);
            a = __builtin_amdgcn_mfma_f32_16x16x32_bf16(kf1, qf1, a, 0, 0, 0);
            sc[nt] = a;
        }

        if (diag) {   // mask kpos > qpos;  kpos-thr = nt*16 + r
            const int thr = q0 + w * 16 + l16 - kt * 128 - quad * 4;
#pragma unroll
            for (int nt = 0; nt < 8; ++nt) {
                if (nt >= ntmax) break;
#pragma unroll
                for (int r = 0; r < 4; ++r)
                    if (nt * 16 + r > thr) sc[nt][r] = -INFINITY;
            }
        }

        // ---- exp2 + row-sum (lane owns one q-row: scalar accumulator)
#pragma unroll
        for (int nt = 0; nt < 8; ++nt) {
            if (nt >= ntmax) break;
#pragma unroll
            for (int r = 0; r < 4; ++r) {
                const float e = exp2f(sc[nt][r]);
                sc[nt][r] = e;
                l_acc += e;
            }
        }

        // ---- P -> PV A-frags, all in registers (no LDS round-trip).
        bf16x8 pA[4];
        const bool qlo = (quad < 2);
#pragma unroll
        for (int c = 0; c < 4; ++c) {
            if (c >= cmax) break;
            unsigned int s0, s1, t0, t1;
            asm("v_cvt_pk_bf16_f32 %0, %1, %2" : "=v"(s0) : "v"(sc[2*c][0]),   "v"(sc[2*c][1]));
            asm("v_cvt_pk_bf16_f32 %0, %1, %2" : "=v"(s1) : "v"(sc[2*c][2]),   "v"(sc[2*c][3]));
            asm("v_cvt_pk_bf16_f32 %0, %1, %2" : "=v"(t0) : "v"(sc[2*c+1][0]), "v"(sc[2*c+1][1]));
            asm("v_cvt_pk_bf16_f32 %0, %1, %2" : "=v"(t1) : "v"(sc[2*c+1][2]), "v"(sc[2*c+1][3]));
            const unsigned int m0 = qlo ? s0 : t0, m1 = qlo ? s1 : t1;
            const unsigned int n0 = qlo ? t0 : s0, n1 = qlo ? t1 : s1;
            const unsigned int X0 = __shfl_xor(m0, 16), X1 = __shfl_xor(m1, 16);
            const unsigned int A0 = __shfl_xor(n0, 32), A1 = __shfl_xor(n1, 32);
            const unsigned int B0 = __shfl_xor(n0, 48), B1 = __shfl_xor(n1, 48);
            u32x4 aw;
            aw[0] = qlo ? (quad == 0 ? m0 : B0) : (quad == 2 ? A0 : X0);
            aw[1] = qlo ? (quad == 0 ? m1 : B1) : (quad == 2 ? A1 : X1);
            aw[2] = qlo ? (quad == 0 ? X0 : A0) : (quad == 2 ? B0 : m0);
            aw[3] = qlo ? (quad == 0 ? X1 : A1) : (quad == 2 ? B1 : m1);
            pA[c] = __builtin_bit_cast(bf16x8, aw);
        }

#pragma unroll
        for (int nt = 0; nt < 4; ++nt) {
            const int row = nt * 16 + l16;
#pragma unroll
            for (int c = 0; c < 4; ++c) {
                if (c >= cmax) break;
                const bf16x8 vF = *(const bf16x8*)(&Vt[cur][row * 128 + (((c * 4 + quad) ^ l16) * 8)]);
                o[nt] = __builtin_amdgcn_mfma_f32_16x16x32_bf16(pA[c], vF, o[nt], 0, 0, 0);
            }
        }

        asm volatile("s_waitcnt lgkmcnt(0)" ::: "memory");
        __builtin_amdgcn_s_barrier();   // barrier B: buf[cur] reads done everywhere
    }
#undef STAGE

    // ---- epilogue: full row-sum = reduce over quads; redistribute to o-rows
    {
        float rs = l_acc;
        rs += __shfl_xor(rs, 16);
        rs += __shfl_xor(rs, 32);       // full sum for q = l16, uniform over quads
        const float linv_row = 1.0f / rs;
        float linv[4];
#pragma unroll
        for (int r = 0; r < 4; ++r)
            linv[r] = __shfl(linv_row, quad * 4 + r);   // l for q = quad*4+r

        const int spos0 = q0 + w * 16 + quad * 4;
#pragma unroll
        for (int nt = 0; nt < 4; ++nt)
#pragma unroll
            for (int r = 0; r < 4; ++r) {
                const float val = o[nt][r] * linv[r];
                O[((size_t)b * S_LEN + spos0 + r) * DMODEL + h * DHEAD + nt * 16 + l16] = f2bf(val);
            }
    }
}

// ---------------------------------------------------------------- out-proj GEMM (bf16 x bf16 -> fp32)
// BK=64 (was 32): 16 K-steps x 2 barriers. LDS 24 KB.
__global__ __launch_bounds__(256, 2) void outproj_kernel(
    const unsigned short* __restrict__ A, const unsigned short* __restrict__ W,
    const float* __restrict__ bias, float* __restrict__ C)
{
    __shared__ __align__(16) unsigned short As[64 * 64];
    __shared__ __align__(16) unsigned short Bs[128 * 64];

    const int tid  = threadIdx.x;
    const int lane = tid & 63;
    const int w    = tid >> 6;
    const int quad = lane >> 4;
    const int l16  = lane & 15;
    const int wm   = (w >> 1) * 32;
    const int wn   = (w & 1) * 64;
    const int bm   = blockIdx.y * 64;
    const int bn   = blockIdx.x * 128;

    f32x4 acc[2][4];
#pragma unroll
    for (int i = 0; i < 2; ++i)
#pragma unroll
        for (int j = 0; j < 4; ++j)
            acc[i][j] = f32x4{0.f, 0.f, 0.f, 0.f};

    const int r8 = tid >> 3, c8 = (tid & 7) * 8;
    const unsigned short* ga = A + (size_t)(bm + r8) * DMODEL + c8;
    const unsigned short* gb = W + (size_t)(bn + r8) * DMODEL + c8;
    unsigned short* la = As + tid * 8;
    unsigned short* lb = Bs + tid * 8;

    for (int k0 = 0; k0 < DMODEL; k0 += 64) {
#pragma unroll
        for (int i = 0; i < 2; ++i)
            glds16(ga + k0 + (size_t)(i * 32) * DMODEL, la + i * 2048);
#pragma unroll
        for (int i = 0; i < 4; ++i)
            glds16(gb + k0 + (size_t)(i * 32) * DMODEL, lb + i * 2048);
        __syncthreads();

        bf16x8 aF[2][2], bF[2][4];
#pragma unroll
        for (int ks = 0; ks < 2; ++ks) {
#pragma unroll
            for (int t = 0; t < 2; ++t)
                aF[ks][t] = *(const bf16x8*)(&As[(wm + t * 16 + l16) * 64 + ks * 32 + quad * 8]);
#pragma unroll
            for (int t = 0; t < 4; ++t)
                bF[ks][t] = *(const bf16x8*)(&Bs[(wn + t * 16 + l16) * 64 + ks * 32 + quad * 8]);
        }
#pragma unroll
        for (int ks = 0; ks < 2; ++ks)
#pragma unroll
            for (int mt = 0; mt < 2; ++mt)
#pragma unroll
                for (int nt = 0; nt < 4; ++nt)
                    acc[mt][nt] = __builtin_amdgcn_mfma_f32_16x16x32_bf16(
                        aF[ks][mt], bF[ks][nt], acc[mt][nt], 0, 0, 0);
        __syncthreads();
    }

#pragma unroll
    for (int mt = 0; mt < 2; ++mt) {
        const int row0 = bm + wm + mt * 16 + quad * 4;
#pragma unroll
        for (int nt = 0; nt < 4; ++nt) {
            const int col = bn + wn + nt * 16 + l16;
            const float bv = bias[col];
#pragma unroll
            for (int r = 0; r < 4; ++r)
                C[(size_t)(row0 + r) * DMODEL + col] = acc[mt][nt][r] + bv;
        }
    }
}

// ---------------------------------------------------------------- launch
extern "C" void kernel_launch(void* const* d_in, const int* in_sizes, int n_in,
                              void* d_out, int out_size, void* d_ws, size_t ws_size,
                              hipStream_t stream) {
    const float* x  = (const float*)d_in[0];
    const float* Wq = (const float*)d_in[1];
    const float* bq = (const float*)d_in[2];
    const float* Wk = (const float*)d_in[3];
    const float* bk = (const float*)d_in[4];
    const float* Wv = (const float*)d_in[5];
    const float* bv = (const float*)d_in[6];
    const float* Wo = (const float*)d_in[7];
    const float* bo = (const float*)d_in[8];
    float* out = (float*)d_out;

    char* ws = (char*)d_ws;
    const size_t MB = 1 << 20;
    unsigned short* xb  = (unsigned short*)(ws);            //  8 MB
    unsigned short* wqb = (unsigned short*)(ws + 8  * MB);  //  2 MB each
    unsigned short* wkb = (unsigned short*)(ws + 10 * MB);
    unsigned short* wvb = (unsigned short*)(ws + 12 * MB);
    unsigned short* wob = (unsigned short*)(ws + 14 * MB);
    float2*         tab = (float2*)       (ws + 16 * MB);   // 512 KB
    unsigned short* Qr  = (unsigned short*)(ws + 17 * MB);  //  8 MB
    unsigned short* Kr  = (unsigned short*)(ws + 25 * MB);
    unsigned short* VT  = (unsigned short*)(ws + 33 * MB);
    unsigned short* AO  = (unsigned short*)(ws + 41 * MB);

    const int M = BATCH * S_LEN;   // 4096

    cvt_kernel<<<dim3(8192), 256, 0, stream>>>(
        x, Wq, Wk, Wv, Wo, xb, wqb, wkb, wvb, wob);

    rope_table_kernel<<<256, 256, 0, stream>>>(tab);

    qkv_gemm_kernel<<<dim3(24, M / 128), 256, 0, stream>>>(
        xb, wqb, wkb, wvb, bq, bk, bv, tab, Qr, Kr, VT);

    attn_kernel<<<dim3(512), 512, 0, stream>>>(Qr, Kr, VT, AO);

    outproj_kernel<<<dim3(DMODEL / 128, M / 64), 256, 0, stream>>>(AO, wob, bo, out);
}